// Round 1
// baseline (1276.899 us; speedup 1.0000x reference)
//
#include <hip/hip_runtime.h>
#include <hip/hip_bf16.h>
#include <stdint.h>

typedef __hip_bfloat16 bf16;
typedef __attribute__((ext_vector_type(8))) short short8;
typedef __attribute__((ext_vector_type(4))) float floatx4;

// ---------- helpers ----------
__device__ __forceinline__ float ldf(const float* p) { return *p; }
__device__ __forceinline__ float ldf(const bf16* p) { return __bfloat162float(*p); }
__device__ __forceinline__ void stf(float* p, float v) { *p = v; }
__device__ __forceinline__ void stf(bf16* p, float v) { *p = __float2bfloat16(v); }

__device__ __forceinline__ unsigned short f2bu(float f) {
  bf16 b = __float2bfloat16(f);
  return *reinterpret_cast<unsigned short*>(&b);
}

// async global->LDS, 16B per lane; lds base must be wave-uniform, HW writes base + lane*16
__device__ __forceinline__ void gl_lds16(const bf16* g, bf16* l) {
  __builtin_amdgcn_global_load_lds((const __attribute__((address_space(1))) void*)g,
                                   (__attribute__((address_space(3))) void*)l,
                                   16, 0, 0);
}

// ---------- conversions ----------
__global__ void cvt_f32_bf16(const float* __restrict__ in, bf16* __restrict__ out, long n4) {
  long i = (long)blockIdx.x * blockDim.x + threadIdx.x;
  if (i >= n4) return;
  float4 v = ((const float4*)in)[i];
  ushort4 o;
  o.x = f2bu(v.x); o.y = f2bu(v.y); o.z = f2bu(v.z); o.w = f2bu(v.w);
  ((ushort4*)out)[i] = o;
}

// in: [R][Cc] f32 -> out: [Cc][R] bf16   (R, Cc multiples of 32)
__global__ void transpose_f32_to_bf16(const float* __restrict__ in, bf16* __restrict__ out,
                                      int R, int Cc) {
  __shared__ float tile[32][33];
  int tx = threadIdx.x & 31;
  int ty = threadIdx.x >> 5;  // 0..7
  int c0 = blockIdx.x * 32;
  int r0 = blockIdx.y * 32;
#pragma unroll
  for (int i = 0; i < 32; i += 8)
    tile[ty + i][tx] = in[(long)(r0 + ty + i) * Cc + c0 + tx];
  __syncthreads();
#pragma unroll
  for (int i = 0; i < 32; i += 8)
    out[(long)(c0 + ty + i) * R + r0 + tx] = __float2bfloat16(tile[tx][ty + i]);
}

// ---------- GEMM: C[M][N] = A[M][K] * BT[N][K]^T, bf16 in, OUT_T out ----------
// 128x128 tile, BK=32, 256 threads (4 waves, 2x2 of 64x64), mfma_f32_16x16x32_bf16
template <typename OUT_T>
__global__ __launch_bounds__(256) void gemm_bt(const bf16* __restrict__ A,
                                               const bf16* __restrict__ BT,
                                               OUT_T* __restrict__ C,
                                               int M, int N, int K) {
  constexpr int BK = 32;
  __shared__ __align__(16) bf16 As[128 * BK];
  __shared__ __align__(16) bf16 Bs[128 * BK];

  const int tid = threadIdx.x;
  const int w = tid >> 6;
  const int lane = tid & 63;
  const int quad = lane >> 4;
  const int r16 = lane & 15;
  const int wm = (w >> 1) * 64;
  const int wn = (w & 1) * 64;

  const long bM = (long)blockIdx.y * 128;
  const long bN = (long)blockIdx.x * 128;

  // staging map: slot s covers rows [s*64 + w*16, +16), lane l -> row +l/4, k=(l&3)*8
  const int srow = w * 16 + (lane >> 2);
  const int sk = (lane & 3) * 8;

  const bf16* Ag0 = A + (bM + srow) * (long)K + sk;
  const bf16* Ag1 = Ag0 + 64L * K;
  const bf16* Bg0 = BT + (bN + srow) * (long)K + sk;
  const bf16* Bg1 = Bg0 + 64L * K;

  bf16* As0 = &As[(0 + w) * 512];
  bf16* As1 = &As[(4 + w) * 512];
  bf16* Bs0 = &Bs[(0 + w) * 512];
  bf16* Bs1 = &Bs[(4 + w) * 512];

  floatx4 acc[4][4];
#pragma unroll
  for (int a = 0; a < 4; a++)
#pragma unroll
    for (int b = 0; b < 4; b++) acc[a][b] = (floatx4){0.f, 0.f, 0.f, 0.f};

  for (int k0 = 0; k0 < K; k0 += BK) {
    gl_lds16(Ag0, As0);
    gl_lds16(Ag1, As1);
    gl_lds16(Bg0, Bs0);
    gl_lds16(Bg1, Bs1);
    Ag0 += BK; Ag1 += BK; Bg0 += BK; Bg1 += BK;
    __syncthreads();

    short8 af[4], bfv[4];
#pragma unroll
    for (int i = 0; i < 4; i++) {
      af[i] = *(const short8*)&As[(wm + i * 16 + r16) * BK + quad * 8];
      bfv[i] = *(const short8*)&Bs[(wn + i * 16 + r16) * BK + quad * 8];
    }
#pragma unroll
    for (int mt = 0; mt < 4; mt++)
#pragma unroll
      for (int nt = 0; nt < 4; nt++)
        acc[mt][nt] = __builtin_amdgcn_mfma_f32_16x16x32_bf16(af[mt], bfv[nt], acc[mt][nt], 0, 0, 0);
    __syncthreads();
  }

  // C/D layout: col = lane&15, row = quad*4 + reg
#pragma unroll
  for (int mt = 0; mt < 4; mt++) {
#pragma unroll
    for (int i = 0; i < 4; i++) {
      long row = bM + wm + mt * 16 + quad * 4 + i;
      OUT_T* crow = C + row * (long)N + bN + wn + r16;
#pragma unroll
      for (int nt = 0; nt < 4; nt++) stf(&crow[nt * 16], acc[mt][nt][i]);
    }
  }
}

// ---------- scan ----------
// c = sigmoid(-gate), v = sigmoid(gate) * g(hidden); g(x) = x>=0 ? x+0.5 : sigmoid(x)
__device__ __forceinline__ void cv_compute(float hval, float gval, float& c, float& v) {
  float eg = __expf(gval);
  c = 1.f / (1.f + eg);
  float z = 1.f - c;
  float gx = (hval >= 0.f) ? (hval + 0.5f) : (1.f / (1.f + __expf(-hval)));
  v = z * gx;
}

// pass1: per (b, chunk, e): P = prod c, V = local recurrence from 0
template <typename T>
__global__ void scan_pass1(const T* __restrict__ hg, float* __restrict__ P,
                           float* __restrict__ V, int S, int Di, int NN, int nch) {
  int tid = blockIdx.x * blockDim.x + threadIdx.x;
  int e = tid % Di;
  int rest = tid / Di;
  int ch = rest % nch;
  int b = rest / nch;
  int CH = S / nch;
  const T* ph = hg + ((long)(b * S + ch * CH)) * NN + e;
  float Pv = 1.f, Vv = 0.f;
  for (int t = 0; t < CH; t++) {
    float c, v;
    cv_compute(ldf(ph), ldf(ph + Di), c, v);
    Pv *= c;
    Vv = fmaf(c, Vv, v);
    ph += NN;
  }
  P[tid] = Pv;
  V[tid] = Vv;
}

// pass2: scan the chunk summaries, store carry-in per chunk
__global__ void scan_pass2(const float* __restrict__ P, const float* __restrict__ V,
                           float* __restrict__ Hc, int Di, int nch) {
  int tid = blockIdx.x * blockDim.x + threadIdx.x;  // b*Di + e
  int e = tid % Di;
  int b = tid / Di;
  float H = 0.f;
  for (int j = 0; j < nch; j++) {
    long idx = ((long)(b * nch + j)) * Di + e;
    Hc[idx] = H;
    H = fmaf(P[idx], H, V[idx]);
  }
}

// pass3: replay chunk with carry, write h (bf16)
template <typename T>
__global__ void scan_pass3(const T* __restrict__ hg, const float* __restrict__ Hc,
                           bf16* __restrict__ h, int S, int Di, int NN, int nch) {
  int tid = blockIdx.x * blockDim.x + threadIdx.x;
  int e = tid % Di;
  int rest = tid / Di;
  int ch = rest % nch;
  int b = rest / nch;
  int CH = S / nch;
  const T* ph = hg + ((long)(b * S + ch * CH)) * NN + e;
  bf16* po = h + ((long)(b * S + ch * CH)) * Di + e;
  float H = Hc[tid];
  for (int t = 0; t < CH; t++) {
    float c, v;
    cv_compute(ldf(ph), ldf(ph + Di), c, v);
    H = fmaf(c, H, v);
    *po = __float2bfloat16(H);
    ph += NN;
    po += Di;
  }
}

// ---------- launch ----------
extern "C" void kernel_launch(void* const* d_in, const int* in_sizes, int n_in,
                              void* d_out, int out_size, void* d_ws, size_t ws_size,
                              hipStream_t stream) {
  const int B = 4, S = 4096, D = 2048, Di = 3072, NN = 6144;
  const int Mr = B * S;       // 16384
  const int NCH = 32;         // chunks per sequence (chunk length 128)

  const float* x = (const float*)d_in[0];
  const float* w_hg = (const float*)d_in[1];
  const float* w_out = (const float*)d_in[2];
  float* out = (float*)d_out;

  char* wp = (char*)d_ws;
  bf16* x_bf = (bf16*)wp;  wp += (size_t)Mr * D * 2;        // 67.1 MB
  bf16* whgT = (bf16*)wp;  wp += (size_t)NN * D * 2;        // 25.2 MB
  bf16* woutT = (bf16*)wp; wp += (size_t)D * Di * 2;        // 12.6 MB
  bf16* h_bf = (bf16*)wp;  wp += (size_t)Mr * Di * 2;       // 100.7 MB
  float* P = (float*)wp;   wp += (size_t)B * NCH * Di * 4;  // 1.6 MB
  float* V = (float*)wp;   wp += (size_t)B * NCH * Di * 4;
  float* Hc = (float*)wp;  wp += (size_t)B * NCH * Di * 4;
  size_t used = (size_t)(wp - (char*)d_ws);
  bool f32hg = (used + (size_t)Mr * NN * 4) <= ws_size;  // constant across calls
  void* hgp = (void*)wp;

  // conversions / transposes
  cvt_f32_bf16<<<(int)(((long)Mr * D / 4 + 255) / 256), 256, 0, stream>>>(x, x_bf, (long)Mr * D / 4);
  transpose_f32_to_bf16<<<dim3(NN / 32, D / 32), 256, 0, stream>>>(w_hg, whgT, D, NN);
  transpose_f32_to_bf16<<<dim3(D / 32, Di / 32), 256, 0, stream>>>(w_out, woutT, Di, D);

  dim3 g1(NN / 128, Mr / 128);  // (48, 128)
  dim3 g2(D / 128, Mr / 128);   // (16, 128)
  int scan_threads = B * NCH * Di;  // 393216

  if (f32hg) {
    float* hg = (float*)hgp;
    gemm_bt<float><<<g1, 256, 0, stream>>>(x_bf, whgT, hg, Mr, NN, D);
    scan_pass1<float><<<scan_threads / 256, 256, 0, stream>>>(hg, P, V, S, Di, NN, NCH);
    scan_pass2<<<(B * Di) / 256, 256, 0, stream>>>(P, V, Hc, Di, NCH);
    scan_pass3<float><<<scan_threads / 256, 256, 0, stream>>>(hg, Hc, h_bf, S, Di, NN, NCH);
  } else {
    bf16* hg = (bf16*)hgp;
    gemm_bt<bf16><<<g1, 256, 0, stream>>>(x_bf, whgT, hg, Mr, NN, D);
    scan_pass1<bf16><<<scan_threads / 256, 256, 0, stream>>>(hg, P, V, S, Di, NN, NCH);
    scan_pass2<<<(B * Di) / 256, 256, 0, stream>>>(P, V, Hc, Di, NCH);
    scan_pass3<bf16><<<scan_threads / 256, 256, 0, stream>>>(hg, Hc, h_bf, S, Di, NN, NCH);
  }

  gemm_bt<float><<<g2, 256, 0, stream>>>(h_bf, woutT, out, Mr, D, Di);
}

// Round 2
// 1254.662 us; speedup vs baseline: 1.0177x; 1.0177x over previous
//
#include <hip/hip_runtime.h>
#include <hip/hip_bf16.h>
#include <stdint.h>

typedef __hip_bfloat16 bf16;
typedef __attribute__((ext_vector_type(8))) short short8;
typedef __attribute__((ext_vector_type(4))) float floatx4;

// ---------- helpers ----------
__device__ __forceinline__ float ldf(const float* p) { return *p; }
__device__ __forceinline__ float ldf(const bf16* p) { return __bfloat162float(*p); }
__device__ __forceinline__ void stf(float* p, float v) { *p = v; }
__device__ __forceinline__ void stf(bf16* p, float v) { *p = __float2bfloat16(v); }

__device__ __forceinline__ unsigned short f2bu(float f) {
  bf16 b = __float2bfloat16(f);
  return *reinterpret_cast<unsigned short*>(&b);
}

// async global->LDS, 16B per lane; lds base must be wave-uniform, HW writes base + lane*16
__device__ __forceinline__ void gl_lds16(const bf16* g, bf16* l) {
  __builtin_amdgcn_global_load_lds((const __attribute__((address_space(1))) void*)g,
                                   (__attribute__((address_space(3))) void*)l,
                                   16, 0, 0);
}

// ---------- conversions ----------
__global__ void cvt_f32_bf16(const float* __restrict__ in, bf16* __restrict__ out, long n4) {
  long i = (long)blockIdx.x * blockDim.x + threadIdx.x;
  if (i >= n4) return;
  float4 v = ((const float4*)in)[i];
  ushort4 o;
  o.x = f2bu(v.x); o.y = f2bu(v.y); o.z = f2bu(v.z); o.w = f2bu(v.w);
  ((ushort4*)out)[i] = o;
}

// in: [R][Cc] f32 -> out: [Cc][R] bf16   (R, Cc multiples of 32)
__global__ void transpose_f32_to_bf16(const float* __restrict__ in, bf16* __restrict__ out,
                                      int R, int Cc) {
  __shared__ float tile[32][33];
  int tx = threadIdx.x & 31;
  int ty = threadIdx.x >> 5;  // 0..7
  int c0 = blockIdx.x * 32;
  int r0 = blockIdx.y * 32;
#pragma unroll
  for (int i = 0; i < 32; i += 8)
    tile[ty + i][tx] = in[(long)(r0 + ty + i) * Cc + c0 + tx];
  __syncthreads();
#pragma unroll
  for (int i = 0; i < 32; i += 8)
    out[(long)(c0 + ty + i) * R + r0 + tx] = __float2bfloat16(tile[tx][ty + i]);
}

// ---------- GEMM: C[M][N] = A[M][K] * BT[N][K]^T, bf16 in, OUT_T out ----------
// 128x128 tile, BK=32, 256 threads (4 waves, 2x2 of 64x64), mfma_f32_16x16x32_bf16
// LDS XOR-swizzle: logical k-chunk q of row r lives at phys chunk q ^ ((r>>1)&3).
// Staging achieves this by permuting the GLOBAL source per lane (global_load_lds
// writes phys = base + lane*16, wave-uniform base — cannot scatter).
template <typename OUT_T>
__global__ __launch_bounds__(256) void gemm_bt(const bf16* __restrict__ A,
                                               const bf16* __restrict__ BT,
                                               OUT_T* __restrict__ C,
                                               int M, int N, int K) {
  constexpr int BK = 32;
  __shared__ __align__(16) bf16 As[128 * BK];
  __shared__ __align__(16) bf16 Bs[128 * BK];

  const int tid = threadIdx.x;
  const int w = tid >> 6;
  const int lane = tid & 63;
  const int quad = lane >> 4;
  const int r16 = lane & 15;
  const int wm = (w >> 1) * 64;
  const int wn = (w & 1) * 64;

  const long bM = (long)blockIdx.y * 128;
  const long bN = (long)blockIdx.x * 128;

  // staging map: slot s covers rows [s*64 + w*16, +16), lane l -> row +l/4,
  // logical k-chunk = (l&3) ^ ((l>>3)&3)  (XOR-swizzle, see above)
  const int srow = w * 16 + (lane >> 2);
  const int sk = (((lane & 3) ^ ((lane >> 3) & 3))) * 8;

  const bf16* Ag0 = A + (bM + srow) * (long)K + sk;
  const bf16* Ag1 = Ag0 + 64L * K;
  const bf16* Bg0 = BT + (bN + srow) * (long)K + sk;
  const bf16* Bg1 = Bg0 + 64L * K;

  bf16* As0 = &As[(0 + w) * 512];
  bf16* As1 = &As[(4 + w) * 512];
  bf16* Bs0 = &Bs[(0 + w) * 512];
  bf16* Bs1 = &Bs[(4 + w) * 512];

  // fragment-read phys chunk offset: quad ^ ((r16>>1)&3)  (lane-constant, row bits 1..2)
  const int cpk = (quad ^ ((r16 >> 1) & 3)) * 8;

  floatx4 acc[4][4];
#pragma unroll
  for (int a = 0; a < 4; a++)
#pragma unroll
    for (int b = 0; b < 4; b++) acc[a][b] = (floatx4){0.f, 0.f, 0.f, 0.f};

  for (int k0 = 0; k0 < K; k0 += BK) {
    gl_lds16(Ag0, As0);
    gl_lds16(Ag1, As1);
    gl_lds16(Bg0, Bs0);
    gl_lds16(Bg1, Bs1);
    Ag0 += BK; Ag1 += BK; Bg0 += BK; Bg1 += BK;
    __syncthreads();

    short8 af[4], bfv[4];
#pragma unroll
    for (int i = 0; i < 4; i++) {
      af[i] = *(const short8*)&As[(wm + i * 16 + r16) * BK + cpk];
      bfv[i] = *(const short8*)&Bs[(wn + i * 16 + r16) * BK + cpk];
    }
#pragma unroll
    for (int mt = 0; mt < 4; mt++)
#pragma unroll
      for (int nt = 0; nt < 4; nt++)
        acc[mt][nt] = __builtin_amdgcn_mfma_f32_16x16x32_bf16(af[mt], bfv[nt], acc[mt][nt], 0, 0, 0);
    __syncthreads();
  }

  // C/D layout: col = lane&15, row = quad*4 + reg
#pragma unroll
  for (int mt = 0; mt < 4; mt++) {
#pragma unroll
    for (int i = 0; i < 4; i++) {
      long row = bM + wm + mt * 16 + quad * 4 + i;
      OUT_T* crow = C + row * (long)N + bN + wn + r16;
#pragma unroll
      for (int nt = 0; nt < 4; nt++) stf(&crow[nt * 16], acc[mt][nt][i]);
    }
  }
}

// ---------- scan ----------
// c = sigmoid(-gate), v = sigmoid(gate) * g(hidden); g(x) = x>=0 ? x+0.5 : sigmoid(x)
__device__ __forceinline__ void cv_compute(float hval, float gval, float& c, float& v) {
  float eg = __expf(gval);
  c = 1.f / (1.f + eg);
  float z = 1.f - c;
  float gx = (hval >= 0.f) ? (hval + 0.5f) : (1.f / (1.f + __expf(-hval)));
  v = z * gx;
}

// pass1: per (b, chunk, e): P = prod c, V = local recurrence from 0
template <typename T>
__global__ void scan_pass1(const T* __restrict__ hg, float* __restrict__ P,
                           float* __restrict__ V, int S, int Di, int NN, int nch) {
  int tid = blockIdx.x * blockDim.x + threadIdx.x;
  int e = tid % Di;
  int rest = tid / Di;
  int ch = rest % nch;
  int b = rest / nch;
  int CH = S / nch;
  const T* ph = hg + ((long)(b * S + ch * CH)) * NN + e;
  float Pv = 1.f, Vv = 0.f;
  for (int t = 0; t < CH; t++) {
    float c, v;
    cv_compute(ldf(ph), ldf(ph + Di), c, v);
    Pv *= c;
    Vv = fmaf(c, Vv, v);
    ph += NN;
  }
  P[tid] = Pv;
  V[tid] = Vv;
}

// pass2: scan the chunk summaries, store carry-in per chunk
__global__ void scan_pass2(const float* __restrict__ P, const float* __restrict__ V,
                           float* __restrict__ Hc, int Di, int nch) {
  int tid = blockIdx.x * blockDim.x + threadIdx.x;  // b*Di + e
  int e = tid % Di;
  int b = tid / Di;
  float H = 0.f;
  for (int j = 0; j < nch; j++) {
    long idx = ((long)(b * nch + j)) * Di + e;
    Hc[idx] = H;
    H = fmaf(P[idx], H, V[idx]);
  }
}

// pass3: replay chunk with carry, write h (bf16)
template <typename T>
__global__ void scan_pass3(const T* __restrict__ hg, const float* __restrict__ Hc,
                           bf16* __restrict__ h, int S, int Di, int NN, int nch) {
  int tid = blockIdx.x * blockDim.x + threadIdx.x;
  int e = tid % Di;
  int rest = tid / Di;
  int ch = rest % nch;
  int b = rest / nch;
  int CH = S / nch;
  const T* ph = hg + ((long)(b * S + ch * CH)) * NN + e;
  bf16* po = h + ((long)(b * S + ch * CH)) * Di + e;
  float H = Hc[tid];
  for (int t = 0; t < CH; t++) {
    float c, v;
    cv_compute(ldf(ph), ldf(ph + Di), c, v);
    H = fmaf(c, H, v);
    *po = __float2bfloat16(H);
    ph += NN;
    po += Di;
  }
}

// ---------- launch ----------
extern "C" void kernel_launch(void* const* d_in, const int* in_sizes, int n_in,
                              void* d_out, int out_size, void* d_ws, size_t ws_size,
                              hipStream_t stream) {
  const int B = 4, S = 4096, D = 2048, Di = 3072, NN = 6144;
  const int Mr = B * S;       // 16384
  const int NCH = 32;         // chunks per sequence (chunk length 128)

  const float* x = (const float*)d_in[0];
  const float* w_hg = (const float*)d_in[1];
  const float* w_out = (const float*)d_in[2];
  float* out = (float*)d_out;

  char* wp = (char*)d_ws;
  bf16* x_bf = (bf16*)wp;  wp += (size_t)Mr * D * 2;        // 67.1 MB
  bf16* whgT = (bf16*)wp;  wp += (size_t)NN * D * 2;        // 25.2 MB
  bf16* woutT = (bf16*)wp; wp += (size_t)D * Di * 2;        // 12.6 MB
  bf16* h_bf = (bf16*)wp;  wp += (size_t)Mr * Di * 2;       // 100.7 MB
  float* P = (float*)wp;   wp += (size_t)B * NCH * Di * 4;  // 1.6 MB
  float* V = (float*)wp;   wp += (size_t)B * NCH * Di * 4;
  float* Hc = (float*)wp;  wp += (size_t)B * NCH * Di * 4;
  size_t used = (size_t)(wp - (char*)d_ws);
  bool f32hg = (used + (size_t)Mr * NN * 4) <= ws_size;  // constant across calls
  void* hgp = (void*)wp;

  // conversions / transposes
  cvt_f32_bf16<<<(int)(((long)Mr * D / 4 + 255) / 256), 256, 0, stream>>>(x, x_bf, (long)Mr * D / 4);
  transpose_f32_to_bf16<<<dim3(NN / 32, D / 32), 256, 0, stream>>>(w_hg, whgT, D, NN);
  transpose_f32_to_bf16<<<dim3(D / 32, Di / 32), 256, 0, stream>>>(w_out, woutT, Di, D);

  dim3 g1(NN / 128, Mr / 128);  // (48, 128)
  dim3 g2(D / 128, Mr / 128);   // (16, 128)
  int scan_threads = B * NCH * Di;  // 393216

  if (f32hg) {
    float* hg = (float*)hgp;
    gemm_bt<float><<<g1, 256, 0, stream>>>(x_bf, whgT, hg, Mr, NN, D);
    scan_pass1<float><<<scan_threads / 256, 256, 0, stream>>>(hg, P, V, S, Di, NN, NCH);
    scan_pass2<<<(B * Di) / 256, 256, 0, stream>>>(P, V, Hc, Di, NCH);
    scan_pass3<float><<<scan_threads / 256, 256, 0, stream>>>(hg, Hc, h_bf, S, Di, NN, NCH);
  } else {
    bf16* hg = (bf16*)hgp;
    gemm_bt<bf16><<<g1, 256, 0, stream>>>(x_bf, whgT, hg, Mr, NN, D);
    scan_pass1<bf16><<<scan_threads / 256, 256, 0, stream>>>(hg, P, V, S, Di, NN, NCH);
    scan_pass2<<<(B * Di) / 256, 256, 0, stream>>>(P, V, Hc, Di, NCH);
    scan_pass3<bf16><<<scan_threads / 256, 256, 0, stream>>>(hg, Hc, h_bf, S, Di, NN, NCH);
  }

  gemm_bt<float><<<g2, 256, 0, stream>>>(h_bf, woutT, out, Mr, D, Di);
}